// Round 1
// baseline (120.285 us; speedup 1.0000x reference)
//
#include <hip/hip_runtime.h>
#include <math.h>

// Fixed problem dims from setup_inputs()
#define BATCH 2
#define C 64
#define HIN 128
#define WIN 128
#define HW (HIN * WIN)
#define OH 256
#define OW 256

#define BLK 256
#define PIX 64    // pixels per block (64 consecutive ox in one oy row)
#define SC 16     // channels per thread-slice (4 slices)
#define ASTR 72   // act row stride in shorts (144 B rows, 16B aligned)
#define YHSTR 17  // y6 row stride in floats (odd -> conflict-free)
#define YSTR 33   // y32 row stride in floats (odd -> conflict-free)
#define OSTR 68   // ofs row stride in floats (272 B, 16B aligned)
#define TCOLS 34  // sampling-1 LDS tile columns (covers x0..x1 span of 64 ox)

// ws bf16 layout (shorts):
//  [    0.. 4095] w1k [n][64]   (w1[n][4+k])
//  [ 4096.. 8191] w2k [n][64]
//  [ 8192..10239] wcm [32][64]  (row eo=e*8+d, k-contig)
//  [10240..12287] wex [256][8]  (row e*64+c, k=d)
//  [12288..13311] whd [16][64]  (rows 0-1 wo, 2-5 wr, 6-15 zero)
#define WS_W2  4096
#define WS_WC  8192
#define WS_WE  10240
#define WS_WH  12288
#define WS_TOT 13312

// Round-10: sampling-1 is block-uniform in oy -> all 64 pixels read the
// same two input rows over a 34-col window. The old 64 per-thread scalar
// gathers re-fetched that 64ch x 2row x 34col tile (4352 floats = exactly
// sizeof(red)) 4x redundantly. Now: 17 cooperative global_load_lds dwords
// per thread stage the tile into red, bilinear runs from LDS (lanes read
// consecutive cols -> <=2-way conflicts, free). conv1 output ping-pongs
// into red-as-bf16 (tile is dead after phase 1), dropping one barrier
// (10 -> 9) and the per-gather 64-bit address VALU.

typedef __attribute__((ext_vector_type(8))) short bf16x8;
typedef __attribute__((ext_vector_type(4))) float f32x4;

__device__ __forceinline__ unsigned short f2bf(float f) {
    unsigned u = __float_as_uint(f);
    u += 0x7FFFu + ((u >> 16) & 1u);          // round-to-nearest-even
    return (unsigned short)(u >> 16);
}

__device__ __forceinline__ void gld_lds4(const float* g, float* l) {
    __builtin_amdgcn_global_load_lds(
        (const __attribute__((address_space(1))) void*)g,
        (__attribute__((address_space(3))) void*)l, 4, 0, 0);
}

__device__ __forceinline__ void bilin_setup(float gx, float gy,
    int& i00, int& i10, int& i01, int& i11,
    float& w00, float& w10, float& w01, float& w11)
{
    const float fx = ((gx + 1.0f) * WIN - 1.0f) * 0.5f;
    const float fy = ((gy + 1.0f) * HIN - 1.0f) * 0.5f;
    const float x0 = floorf(fx), y0 = floorf(fy);
    const float wx1 = fx - x0, wx0 = 1.0f - wx1;
    const float wy1 = fy - y0, wy0 = 1.0f - wy1;
    const float x1 = x0 + 1.0f, y1 = y0 + 1.0f;
    const bool vx0 = (x0 >= 0.0f) && (x0 <= (float)(WIN - 1));
    const bool vx1 = (x1 >= 0.0f) && (x1 <= (float)(WIN - 1));
    const bool vy0 = (y0 >= 0.0f) && (y0 <= (float)(HIN - 1));
    const bool vy1 = (y1 >= 0.0f) && (y1 <= (float)(HIN - 1));
    const int xi0 = (int)fminf(fmaxf(x0, 0.0f), (float)(WIN - 1));
    const int xi1 = (int)fminf(fmaxf(x1, 0.0f), (float)(WIN - 1));
    const int yi0 = (int)fminf(fmaxf(y0, 0.0f), (float)(HIN - 1));
    const int yi1 = (int)fminf(fmaxf(y1, 0.0f), (float)(HIN - 1));
    w00 = wx0 * wy0 * ((vx0 && vy0) ? 1.0f : 0.0f);
    w10 = wx1 * wy0 * ((vx1 && vy0) ? 1.0f : 0.0f);
    w01 = wx0 * wy1 * ((vx0 && vy1) ? 1.0f : 0.0f);
    w11 = wx1 * wy1 * ((vx1 && vy1) ? 1.0f : 0.0f);
    i00 = yi0 * WIN + xi0;  i10 = yi0 * WIN + xi1;
    i01 = yi1 * WIN + xi0;  i11 = yi1 * WIN + xi1;
}

__global__ __launch_bounds__(256) void prep_kernel(
    const float* __restrict__ wcm, const float* __restrict__ wex,
    const float* __restrict__ w1,  const float* __restrict__ w2,
    const float* __restrict__ wr,  const float* __restrict__ wo,
    unsigned short* __restrict__ wsb)
{
    const int i = blockIdx.x * 256 + threadIdx.x;
    if (i >= WS_TOT) return;
    float v = 0.0f;
    if (i < WS_W2) {                       // w1k
        const int n = i >> 6, k = i & 63;
        v = w1[n * (C + 4) + 4 + k];
    } else if (i < WS_WC) {                // w2k
        v = w2[i - WS_W2];
    } else if (i < WS_WE) {                // wcm
        v = wcm[i - WS_WC];
    } else if (i < WS_WH) {                // wex
        v = wex[i - WS_WE];
    } else {                               // whd (zero-padded to 16 rows)
        const int j = i - WS_WH;
        const int n = j >> 6, k = j & 63;
        v = (n < 2) ? wo[n * C + k] : ((n < 6) ? wr[(n - 2) * C + k] : 0.0f);
    }
    wsb[i] = f2bf(v);
}

__global__ __launch_bounds__(BLK, 4) void scab_kernel(
    const float* __restrict__ x,    // (B, C, HIN, WIN)
    const float* __restrict__ w1,   // (64, 68)  (coord cols + bias fold)
    const float* __restrict__ b1,   // (64)
    const float* __restrict__ b2,   // (64)
    const float* __restrict__ br,   // (4)
    const float* __restrict__ bo,   // (2)
    const unsigned short* __restrict__ wsb,  // pre-packed bf16 weights
    float* __restrict__ out)        // (B, C, OH, OW)
{
    __shared__ __align__(16) short act[PIX * ASTR];   // 9216 B
    __shared__ __align__(16) float red[PIX * OSTR];   // 17408 B
    float* const xt  = red;                // phase-1 input tile (4352 floats)
    short* const act2 = (short*)red;       // phase-2 relu1 ping-pong (4608 sh)

    const int tid  = threadIdx.x;
    const int lane = tid & 63;                                  // pixel within block
    const int s    = __builtin_amdgcn_readfirstlane(tid >> 6);  // slice == wave id
    const int cb   = s * SC;
    const int l15  = lane & 15;
    const int quad = lane >> 4;
    const int nn   = cb + l15;                                  // my MFMA out-col

    const int gp = blockIdx.x * PIX + lane;
    const int ox = gp & (OW - 1);
    const int oy = (gp >> 8) & (OH - 1);
    const int bb = gp >> 16;

    // ---- base grid (fp32, matches reference) ----
    const float gx = ((ox + 0.5f) * 0.5f - 0.5f) * (2.0f / (WIN - 1)) - 1.0f;
    const float gy = ((oy + 0.5f) * 0.5f - 0.5f) * (2.0f / (HIN - 1)) - 1.0f;

    const float* __restrict__ xb = x + bb * (C * HW);

    // ===== phase 0: cooperative x-tile stage (block-uniform rows y0,y1) =====
    // fy / rows are uniform across the block (oy uniform); column window is
    // [g0, g0+33] where g0 = floor(fx(first ox of block)).
    const float fy  = ((gy + 1.0f) * HIN - 1.0f) * 0.5f;
    const float y0f = floorf(fy);
    const int yi0 = (int)fminf(fmaxf(y0f, 0.0f), (float)(HIN - 1));
    const int yi1 = (int)fminf(fmaxf(y0f + 1.0f, 0.0f), (float)(HIN - 1));
    const int ox0 = ox & ~63;
    const float gx0 = ((ox0 + 0.5f) * 0.5f - 0.5f) * (2.0f / (WIN - 1)) - 1.0f;
    const float fx0 = ((gx0 + 1.0f) * WIN - 1.0f) * 0.5f;
    const int g0 = (int)floorf(fx0);

    #pragma unroll
    for (int t = 0; t < 17; ++t) {
        const int idx = t * 256 + tid;                       // linear tile idx
        const int rc  = (int)(((unsigned)idx * 61681u) >> 21);  // idx / 34
        const int col = idx - rc * 34;
        const int gc  = min(max(g0 + col, 0), WIN - 1);      // clamped col
        const int yr  = (rc & 1) ? yi1 : yi0;
        gld_lds4(xb + (rc >> 1) * HW + yr * WIN + gc, &xt[idx]);
    }

    // ===== B-frags: single dwordx4 loads from pre-packed ws =====
    const int nt1  = s & 1;                  // GEMM-1 n-tile of this wave
    const int eo_g = nt1 * 16 + l15;         // GEMM-1 out index (e*8+d)
    bf16x8 bw1[2], bw2[2], bwc[2], bhd[2], bwe;
    #pragma unroll
    for (int ks = 0; ks < 2; ++ks) {
        bw1[ks] = *(const bf16x8*)(wsb +         nn   * 64 + ks * 32 + quad * 8);
        bw2[ks] = *(const bf16x8*)(wsb + WS_W2 + nn   * 64 + ks * 32 + quad * 8);
        bwc[ks] = *(const bf16x8*)(wsb + WS_WC + eo_g * 64 + ks * 32 + quad * 8);
        bhd[ks] = *(const bf16x8*)(wsb + WS_WH + l15  * 64 + ks * 32 + quad * 8);
    }
    bwe = *(const bf16x8*)(wsb + WS_WE + (quad * C + nn) * 8);

    // sampling-1 weights / tile-local cols (same arithmetic as reference)
    const float fx  = ((gx + 1.0f) * WIN - 1.0f) * 0.5f;
    const float x0f = floorf(fx);
    const float wx1 = fx - x0f, wx0 = 1.0f - wx1;
    const float wy1 = fy - y0f, wy0 = 1.0f - wy1;
    const bool vx0 = (x0f >= 0.0f) && (x0f <= (float)(WIN - 1));
    const bool vx1 = (x0f + 1.0f >= 0.0f) && (x0f + 1.0f <= (float)(WIN - 1));
    const bool vy0 = (y0f >= 0.0f) && (y0f <= (float)(HIN - 1));
    const bool vy1 = (y0f + 1.0f >= 0.0f) && (y0f + 1.0f <= (float)(HIN - 1));
    const float w00 = wx0 * wy0 * ((vx0 && vy0) ? 1.0f : 0.0f);
    const float w10 = wx1 * wy0 * ((vx1 && vy0) ? 1.0f : 0.0f);
    const float w01 = wx0 * wy1 * ((vx0 && vy1) ? 1.0f : 0.0f);
    const float w11 = wx1 * wy1 * ((vx1 && vy1) ? 1.0f : 0.0f);
    const int lx0 = (int)fminf(fmaxf(x0f, 0.0f), (float)(WIN - 1)) - g0;
    const int lx1 = (int)fminf(fmaxf(x0f + 1.0f, 0.0f), (float)(WIN - 1)) - g0;

    __syncthreads();   // B0: tile resident (barrier drains vmcnt)

    // ===== phase 1: bilinear from LDS tile, bf16 act[pix][ch] =====
    {
        bf16x8 v0, v1;
        #pragma unroll
        for (int kk = 0; kk < SC; ++kk) {
            const float* T = xt + (cb + kk) * (2 * TCOLS);
            const float pf = T[lx0] * w00 + T[lx1] * w10
                           + T[TCOLS + lx0] * w01 + T[TCOLS + lx1] * w11;
            const short b = (short)f2bf(pf);
            if (kk < 8) v0[kk] = b; else v1[kk - 8] = b;
        }
        *(bf16x8*)&act[lane * ASTR + cb]     = v0;
        *(bf16x8*)&act[lane * ASTR + cb + 8] = v1;
    }
    __syncthreads();   // B1: act(pf) ready; tile dead

    // ===== phase 2: conv1 via MFMA; coords+bias folded into C-init =====
    const float coor_h = (oy & 1) ? 0.25f : -0.25f;
    f32x4 acc[4];
    {
        const float4 wh = *(const float4*)(w1 + nn * (C + 4));   // w1[n][0..3]
        const float qn = b1[nn] + (wh.x + wh.y) * 0.5f + wh.z * coor_h;
        const float e0 = qn - 0.25f * wh.w;    // even pixel rows (reg 0,2)
        const float e1 = qn + 0.25f * wh.w;    // odd  pixel rows (reg 1,3)
        #pragma unroll
        for (int t = 0; t < 4; ++t) acc[t] = (f32x4){e0, e1, e0, e1};
    }
    #pragma unroll
    for (int t = 0; t < 4; ++t) {
        #pragma unroll
        for (int ks = 0; ks < 2; ++ks) {
            const bf16x8 af = *(const bf16x8*)&act[(t*16 + l15) * ASTR + ks*32 + quad*8];
            acc[t] = __builtin_amdgcn_mfma_f32_16x16x32_bf16(af, bw1[ks], acc[t], 0, 0, 0);
        }
    }
    // relu1 -> act2 (red region; disjoint from act, no extra barrier)
    #pragma unroll
    for (int t = 0; t < 4; ++t)
        #pragma unroll
        for (int r = 0; r < 4; ++r)
            act2[(t*16 + quad*4 + r) * ASTR + nn] = (short)f2bf(fmaxf(acc[t][r], 0.0f));
    __syncthreads();   // B2: act2(relu1) ready

    // ===== phase 3: conv2 via MFMA (read act2, write act) =====
    {
        const float b2n = b2[nn];
        #pragma unroll
        for (int t = 0; t < 4; ++t) acc[t] = (f32x4){b2n, b2n, b2n, b2n};
    }
    #pragma unroll
    for (int t = 0; t < 4; ++t) {
        #pragma unroll
        for (int ks = 0; ks < 2; ++ks) {
            const bf16x8 af = *(const bf16x8*)&act2[(t*16 + l15) * ASTR + ks*32 + quad*8];
            acc[t] = __builtin_amdgcn_mfma_f32_16x16x32_bf16(af, bw2[ks], acc[t], 0, 0, 0);
        }
    }
    #pragma unroll
    for (int t = 0; t < 4; ++t)
        #pragma unroll
        for (int r = 0; r < 4; ++r)
            act[(t*16 + quad*4 + r) * ASTR + nn] = (short)f2bf(fmaxf(acc[t][r], 0.0f));
    __syncthreads();   // B3: act(emb) ready

    // ===== phase 4: heads via MFMA (wave s = m-tile s; n<6 used) =====
    {
        f32x4 yac = (f32x4){0.0f, 0.0f, 0.0f, 0.0f};
        #pragma unroll
        for (int ks = 0; ks < 2; ++ks) {
            const bf16x8 af = *(const bf16x8*)&act[(s*16 + l15) * ASTR + ks*32 + quad*8];
            yac = __builtin_amdgcn_mfma_f32_16x16x32_bf16(af, bhd[ks], yac, 0, 0, 0);
        }
        #pragma unroll
        for (int r = 0; r < 4; ++r)
            red[(s*16 + quad*4 + r) * YHSTR + l15] = yac[r];
    }
    __syncthreads();   // B4: y6 ready

    // ===== phase 5: offsets/gates from y6 (identical in all slices), then
    //        sampling-2 (per-pixel offsets); fea0 fp32 in regs + bf16 LDS =====
    const float* __restrict__ yp = &red[lane * YHSTR];
    const float offx = bo[0] + yp[0];
    const float offy = bo[1] + yp[1];
    const float rg0 = 1.0f / (1.0f + __expf(-(br[0] + yp[2])));
    const float rg1 = 1.0f / (1.0f + __expf(-(br[1] + yp[3])));
    const float rg2 = 1.0f / (1.0f + __expf(-(br[2] + yp[4])));
    const float rg3 = 1.0f / (1.0f + __expf(-(br[3] + yp[5])));

    float f[SC];
    {
        int j00, j10, j01, j11;
        float v00, v10, v01, v11;
        bilin_setup(gx + offx * (2.0f / (WIN - 1)),
                    gy + offy * (2.0f / (HIN - 1)),
                    j00, j10, j01, j11, v00, v10, v01, v11);
        bf16x8 v0, v1;
        #pragma unroll
        for (int kk = 0; kk < SC; kk += 4) {
            float l[16];
            #pragma unroll
            for (int k = 0; k < 4; ++k) {
                const float* __restrict__ xc = xb + (cb + kk + k) * HW;
                l[4*k+0] = xc[j00]; l[4*k+1] = xc[j10];
                l[4*k+2] = xc[j01]; l[4*k+3] = xc[j11];
            }
            #pragma unroll
            for (int k = 0; k < 4; ++k) {
                const float fc = l[4*k]*v00 + l[4*k+1]*v10 + l[4*k+2]*v01 + l[4*k+3]*v11;
                f[kk + k] = fc;
                const short b = (short)f2bf(fc);
                if (kk + k < 8) v0[kk + k] = b; else v1[kk + k - 8] = b;
            }
        }
        *(bf16x8*)&act[lane * ASTR + cb]     = v0;   // overwrite emb
        *(bf16x8*)&act[lane * ASTR + cb + 8] = v1;
    }
    __syncthreads();   // B5: act(fea0) visible; all y6 reads done

    // ===== phase 6: GEMM-1  y[pix][eo] = fea0 x wcm^T  (2 m-tiles/wave) =====
    {
        const int mb = (s >> 1) * 2;
        #pragma unroll
        for (int mi = 0; mi < 2; ++mi) {
            const int mt = mb + mi;
            f32x4 yac = (f32x4){0.0f, 0.0f, 0.0f, 0.0f};
            #pragma unroll
            for (int ks = 0; ks < 2; ++ks) {
                const bf16x8 af = *(const bf16x8*)&act[(mt*16 + l15) * ASTR + ks*32 + quad*8];
                yac = __builtin_amdgcn_mfma_f32_16x16x32_bf16(af, bwc[ks], yac, 0, 0, 0);
            }
            #pragma unroll
            for (int r = 0; r < 4; ++r)
                red[(mt*16 + quad*4 + r) * YSTR + nt1*16 + l15] = yac[r];
        }
    }
    __syncthreads();   // B6: y32 ready

    // ===== phase 7: per-pixel gate fold: comp[d], t[ed] -> bf16 act[pix][0..31] =====
    {
        float comp[8];
        const float* __restrict__ yr = &red[lane * YSTR];
        #pragma unroll
        for (int d = 0; d < 8; ++d) {
            float v = rg0 * yr[d];
            v = fmaf(rg1, yr[8 + d],  v);
            v = fmaf(rg2, yr[16 + d], v);
            v = fmaf(rg3, yr[24 + d], v);
            comp[d] = v;
        }
        bf16x8 t0, t1;
        #pragma unroll
        for (int d = 0; d < 8; ++d) {
            t0[d] = (short)f2bf(rg0 * comp[d]);
            t1[d] = (short)f2bf(rg1 * comp[d]);
        }
        bf16x8 t2, t3;
        #pragma unroll
        for (int d = 0; d < 8; ++d) {
            t2[d] = (short)f2bf(rg2 * comp[d]);
            t3[d] = (short)f2bf(rg3 * comp[d]);
        }
        // GEMM-1's act reads completed before B6; t writes target act while
        // y32 reads hit red -- disjoint arrays. Safe.
        *(bf16x8*)&act[lane * ASTR + 0]  = t0;
        *(bf16x8*)&act[lane * ASTR + 8]  = t1;
        *(bf16x8*)&act[lane * ASTR + 16] = t2;
        *(bf16x8*)&act[lane * ASTR + 24] = t3;
    }
    __syncthreads();   // B7: t-matrix ready

    // ===== phase 8: GEMM-2  expand[pix][c] = t x wexR^T  (4 m-tiles/wave) =====
    #pragma unroll
    for (int t = 0; t < 4; ++t) {
        f32x4 oac = (f32x4){0.0f, 0.0f, 0.0f, 0.0f};
        const bf16x8 af = *(const bf16x8*)&act[(t*16 + l15) * ASTR + quad*8];
        oac = __builtin_amdgcn_mfma_f32_16x16x32_bf16(af, bwe, oac, 0, 0, 0);
        #pragma unroll
        for (int r = 0; r < 4; ++r)
            red[(t*16 + quad*4 + r) * OSTR + nn] = oac[r];
    }
    __syncthreads();   // B8: expand ready

    // ===== phase 9: residual + coalesced store (pixel=lane, my 16 ch) =====
    float* __restrict__ ob = out + bb * (C * OH * OW) + oy * OW + ox;
    const float* __restrict__ orow = &red[lane * OSTR + cb];
    #pragma unroll
    for (int kk = 0; kk < SC; kk += 4) {
        const float4 e4 = *(const float4*)(orow + kk);
        ob[(cb + kk + 0) * (OH * OW)] = f[kk + 0] + e4.x;
        ob[(cb + kk + 1) * (OH * OW)] = f[kk + 1] + e4.y;
        ob[(cb + kk + 2) * (OH * OW)] = f[kk + 2] + e4.z;
        ob[(cb + kk + 3) * (OH * OW)] = f[kk + 3] + e4.w;
    }
}

extern "C" void kernel_launch(void* const* d_in, const int* in_sizes, int n_in,
                              void* d_out, int out_size, void* d_ws, size_t ws_size,
                              hipStream_t stream) {
    const float* x   = (const float*)d_in[0];
    const float* wcm = (const float*)d_in[1];
    const float* wex = (const float*)d_in[2];
    const float* w1  = (const float*)d_in[3];
    const float* b1  = (const float*)d_in[4];
    const float* w2  = (const float*)d_in[5];
    const float* b2  = (const float*)d_in[6];
    const float* wr  = (const float*)d_in[7];
    const float* br  = (const float*)d_in[8];
    const float* wo  = (const float*)d_in[9];
    const float* bo  = (const float*)d_in[10];
    float* out = (float*)d_out;
    unsigned short* wsb = (unsigned short*)d_ws;

    // prep: pack weights to bf16 in ws (same work every call; stream-ordered)
    prep_kernel<<<(WS_TOT + 255) / 256, 256, 0, stream>>>(wcm, wex, w1, w2, wr, wo, wsb);

    const int total  = BATCH * OH * OW;    // 131072 pixels
    const int blocks = total / PIX;        // 2048 blocks of 256 threads
    scab_kernel<<<blocks, BLK, 0, stream>>>(x, w1, b1, b2, br, bo, wsb, out);
}

// Round 2
// 118.702 us; speedup vs baseline: 1.0133x; 1.0133x over previous
//
#include <hip/hip_runtime.h>
#include <math.h>

// Fixed problem dims from setup_inputs()
#define BATCH 2
#define C 64
#define HIN 128
#define WIN 128
#define HW (HIN * WIN)
#define OH 256
#define OW 256

#define BLK 256
#define PIX 64    // pixels per block (64 consecutive ox in one oy row)
#define SC 16     // channels per thread-slice (4 slices)
#define ASTR 72   // act row stride in shorts (144 B rows, 16B aligned)
#define YHSTR 17  // y6 row stride in floats (odd -> conflict-free)
#define YSTR 33   // y32 row stride in floats (odd -> conflict-free)
#define OSTR 68   // ofs row stride in floats (272 B, 16B aligned)

// ws bf16 layout (shorts):
//  [    0.. 4095] w1k [n][64]   (w1[n][4+k])
//  [ 4096.. 8191] w2k [n][64]
//  [ 8192..10239] wcm [32][64]  (row eo=e*8+d, k-contig)
//  [10240..12287] wex [256][8]  (row e*64+c, k=d)
//  [12288..13311] whd [16][64]  (rows 0-1 wo, 2-5 wr, 6-15 zero)
#define WS_W2  4096
#define WS_WC  8192
#define WS_WE  10240
#define WS_WH  12288
#define WS_TOT 13312

// Round-11: (a) pair-gathers -- bilinear corners x0,x1 are adjacent cols,
// so each (row,channel) is ONE dwordx2 instead of two dwords (128 -> 64
// gather instrs/thread). Clamped-edge cases always carry weight 0, so the
// column-select folds into per-pixel weights u0/u1/t0/t1 (bitwise-identical,
// zero selects in the channel loop). (b) all f2bf chains (5 VALU each)
// replaced by v_cvt_pk_bf16_f32 (1 instr / 2 values, same RNE) -- saves
// ~350 VALU ops/thread. (c) relu ping-pong act->act2(red) keeps barrier
// count at 8 (was 10 in round-9). LDS tile from round-10 reverted (measured
// neutral; sampling-1 gathers were already latency-hidden L2 hits).

typedef __attribute__((ext_vector_type(8))) short bf16x8;
typedef __attribute__((ext_vector_type(4))) float f32x4;
typedef __attribute__((ext_vector_type(4))) unsigned u32x4;

__device__ __forceinline__ unsigned short f2bf(float f) {
    unsigned u = __float_as_uint(f);
    u += 0x7FFFu + ((u >> 16) & 1u);          // round-to-nearest-even
    return (unsigned short)(u >> 16);
}

// packed f32x2 -> bf16x2 (RNE, same result as f2bf on finite values)
__device__ __forceinline__ unsigned cvtpk(float lo, float hi) {
    unsigned r;
    asm("v_cvt_pk_bf16_f32 %0, %1, %2" : "=v"(r) : "v"(lo), "v"(hi));
    return r;
}

// Bilinear setup with pair-load folding: returns two row base indices
// (p0=top,p1=bottom, column-clamped to <=WIN-2 so a dwordx2 stays in-row)
// and 4 folded weights: pf = a.x*u0 + a.y*u1 + b.x*t0 + b.y*t1 where
// a = x[p0..p0+1], b = x[p1..p1+1]. Identical to the reference 4-corner
// weighted sum: whenever a clamped index diverges from x0/x0+1 the
// corresponding reference weight is exactly 0.
__device__ __forceinline__ void bilin_pair(float gx, float gy,
    int& p0, int& p1, float& u0, float& u1, float& t0, float& t1)
{
    const float fx = ((gx + 1.0f) * WIN - 1.0f) * 0.5f;
    const float fy = ((gy + 1.0f) * HIN - 1.0f) * 0.5f;
    const float x0 = floorf(fx), y0 = floorf(fy);
    const float wx1 = fx - x0, wx0 = 1.0f - wx1;
    const float wy1 = fy - y0, wy0 = 1.0f - wy1;
    const bool vx0 = (x0 >= 0.0f) && (x0 <= (float)(WIN - 1));
    const bool vx1 = (x0 + 1.0f >= 0.0f) && (x0 + 1.0f <= (float)(WIN - 1));
    const bool vy0 = (y0 >= 0.0f) && (y0 <= (float)(HIN - 1));
    const bool vy1 = (y0 + 1.0f >= 0.0f) && (y0 + 1.0f <= (float)(HIN - 1));
    const float w00 = wx0 * wy0 * ((vx0 && vy0) ? 1.0f : 0.0f);
    const float w10 = wx1 * wy0 * ((vx1 && vy0) ? 1.0f : 0.0f);
    const float w01 = wx0 * wy1 * ((vx0 && vy1) ? 1.0f : 0.0f);
    const float w11 = wx1 * wy1 * ((vx1 && vy1) ? 1.0f : 0.0f);
    const int xi0 = (int)fminf(fmaxf(x0, 0.0f), (float)(WIN - 1));
    const int xi1 = (int)fminf(fmaxf(x0 + 1.0f, 0.0f), (float)(WIN - 1));
    const int yi0 = (int)fminf(fmaxf(y0, 0.0f), (float)(HIN - 1));
    const int yi1 = (int)fminf(fmaxf(y0 + 1.0f, 0.0f), (float)(HIN - 1));
    const int bx = min(xi0, WIN - 2);
    const int s0 = xi0 - bx, s1 = xi1 - bx;   // each 0 or 1
    u0 = (s0 ? 0.0f : w00) + (s1 ? 0.0f : w10);
    u1 = (s0 ? w00 : 0.0f) + (s1 ? w10 : 0.0f);
    t0 = (s0 ? 0.0f : w01) + (s1 ? 0.0f : w11);
    t1 = (s0 ? w01 : 0.0f) + (s1 ? w11 : 0.0f);
    p0 = yi0 * WIN + bx;
    p1 = yi1 * WIN + bx;
}

__global__ __launch_bounds__(256) void prep_kernel(
    const float* __restrict__ wcm, const float* __restrict__ wex,
    const float* __restrict__ w1,  const float* __restrict__ w2,
    const float* __restrict__ wr,  const float* __restrict__ wo,
    unsigned short* __restrict__ wsb)
{
    const int i = blockIdx.x * 256 + threadIdx.x;
    if (i >= WS_TOT) return;
    float v = 0.0f;
    if (i < WS_W2) {                       // w1k
        const int n = i >> 6, k = i & 63;
        v = w1[n * (C + 4) + 4 + k];
    } else if (i < WS_WC) {                // w2k
        v = w2[i - WS_W2];
    } else if (i < WS_WE) {                // wcm
        v = wcm[i - WS_WC];
    } else if (i < WS_WH) {                // wex
        v = wex[i - WS_WE];
    } else {                               // whd (zero-padded to 16 rows)
        const int j = i - WS_WH;
        const int n = j >> 6, k = j & 63;
        v = (n < 2) ? wo[n * C + k] : ((n < 6) ? wr[(n - 2) * C + k] : 0.0f);
    }
    wsb[i] = f2bf(v);
}

__global__ __launch_bounds__(BLK, 4) void scab_kernel(
    const float* __restrict__ x,    // (B, C, HIN, WIN)
    const float* __restrict__ w1,   // (64, 68)  (coord cols + bias fold)
    const float* __restrict__ b1,   // (64)
    const float* __restrict__ b2,   // (64)
    const float* __restrict__ br,   // (4)
    const float* __restrict__ bo,   // (2)
    const unsigned short* __restrict__ wsb,  // pre-packed bf16 weights
    float* __restrict__ out)        // (B, C, OH, OW)
{
    __shared__ __align__(16) short act[PIX * ASTR];   // 9216 B
    __shared__ __align__(16) float red[PIX * OSTR];   // 17408 B
    short* const act2 = (short*)red;       // relu1 ping-pong (4608 shorts)

    const int tid  = threadIdx.x;
    const int lane = tid & 63;                                  // pixel within block
    const int s    = __builtin_amdgcn_readfirstlane(tid >> 6);  // slice == wave id
    const int cb   = s * SC;
    const int l15  = lane & 15;
    const int quad = lane >> 4;
    const int nn   = cb + l15;                                  // my MFMA out-col

    const int gp = blockIdx.x * PIX + lane;
    const int ox = gp & (OW - 1);
    const int oy = (gp >> 8) & (OH - 1);
    const int bb = gp >> 16;

    // ---- base grid (fp32, matches reference) ----
    const float gx = ((ox + 0.5f) * 0.5f - 0.5f) * (2.0f / (WIN - 1)) - 1.0f;
    const float gy = ((oy + 0.5f) * 0.5f - 0.5f) * (2.0f / (HIN - 1)) - 1.0f;

    const float* __restrict__ xb = x + bb * (C * HW);

    // ===== B-frags: single dwordx4 loads from pre-packed ws =====
    const int nt1  = s & 1;                  // GEMM-1 n-tile of this wave
    const int eo_g = nt1 * 16 + l15;         // GEMM-1 out index (e*8+d)
    bf16x8 bw1[2], bw2[2], bwc[2], bhd[2], bwe;
    #pragma unroll
    for (int ks = 0; ks < 2; ++ks) {
        bw1[ks] = *(const bf16x8*)(wsb +         nn   * 64 + ks * 32 + quad * 8);
        bw2[ks] = *(const bf16x8*)(wsb + WS_W2 + nn   * 64 + ks * 32 + quad * 8);
        bwc[ks] = *(const bf16x8*)(wsb + WS_WC + eo_g * 64 + ks * 32 + quad * 8);
        bhd[ks] = *(const bf16x8*)(wsb + WS_WH + l15  * 64 + ks * 32 + quad * 8);
    }
    bwe = *(const bf16x8*)(wsb + WS_WE + (quad * C + nn) * 8);

    // ===== phase 1: sampling-1 pair-gathers (my 16 ch) -> bf16 act =====
    {
        int p0, p1;
        float u0, u1, t0, t1;
        bilin_pair(gx, gy, p0, p1, u0, u1, t0, t1);
        float pf[SC];
        #pragma unroll
        for (int kb = 0; kb < SC; kb += 8) {
            float2 a[8], b[8];
            #pragma unroll
            for (int k = 0; k < 8; ++k) {
                const float* __restrict__ xc = xb + (cb + kb + k) * HW;
                a[k] = *(const float2*)(xc + p0);
                b[k] = *(const float2*)(xc + p1);
            }
            #pragma unroll
            for (int k = 0; k < 8; ++k)
                pf[kb + k] = fmaf(a[k].x, u0, fmaf(a[k].y, u1,
                             fmaf(b[k].x, t0, b[k].y * t1)));
        }
        u32x4 v0, v1;
        #pragma unroll
        for (int d = 0; d < 4; ++d) {
            v0[d] = cvtpk(pf[2*d],     pf[2*d + 1]);
            v1[d] = cvtpk(pf[8 + 2*d], pf[8 + 2*d + 1]);
        }
        *(u32x4*)&act[lane * ASTR + cb]     = v0;
        *(u32x4*)&act[lane * ASTR + cb + 8] = v1;
    }
    __syncthreads();   // B1: act(pf) ready

    // ===== phase 2: conv1 via MFMA; coords+bias folded into C-init =====
    const float coor_h = (oy & 1) ? 0.25f : -0.25f;
    f32x4 acc[4];
    {
        const float4 wh = *(const float4*)(w1 + nn * (C + 4));   // w1[n][0..3]
        const float qn = b1[nn] + (wh.x + wh.y) * 0.5f + wh.z * coor_h;
        const float e0 = qn - 0.25f * wh.w;    // even pixel rows (reg 0,2)
        const float e1 = qn + 0.25f * wh.w;    // odd  pixel rows (reg 1,3)
        #pragma unroll
        for (int t = 0; t < 4; ++t) acc[t] = (f32x4){e0, e1, e0, e1};
    }
    #pragma unroll
    for (int t = 0; t < 4; ++t) {
        #pragma unroll
        for (int ks = 0; ks < 2; ++ks) {
            const bf16x8 af = *(const bf16x8*)&act[(t*16 + l15) * ASTR + ks*32 + quad*8];
            acc[t] = __builtin_amdgcn_mfma_f32_16x16x32_bf16(af, bw1[ks], acc[t], 0, 0, 0);
        }
    }
    // relu1 -> act2 (red region; disjoint from act, no extra barrier)
    #pragma unroll
    for (int t = 0; t < 4; ++t) {
        const unsigned p01 = cvtpk(fmaxf(acc[t][0], 0.0f), fmaxf(acc[t][1], 0.0f));
        const unsigned p23 = cvtpk(fmaxf(acc[t][2], 0.0f), fmaxf(acc[t][3], 0.0f));
        act2[(t*16 + quad*4 + 0) * ASTR + nn] = (short)(p01 & 0xffffu);
        act2[(t*16 + quad*4 + 1) * ASTR + nn] = (short)(p01 >> 16);
        act2[(t*16 + quad*4 + 2) * ASTR + nn] = (short)(p23 & 0xffffu);
        act2[(t*16 + quad*4 + 3) * ASTR + nn] = (short)(p23 >> 16);
    }
    __syncthreads();   // B2: act2(relu1) ready

    // ===== phase 3: conv2 via MFMA (read act2, write act) =====
    {
        const float b2n = b2[nn];
        #pragma unroll
        for (int t = 0; t < 4; ++t) acc[t] = (f32x4){b2n, b2n, b2n, b2n};
    }
    #pragma unroll
    for (int t = 0; t < 4; ++t) {
        #pragma unroll
        for (int ks = 0; ks < 2; ++ks) {
            const bf16x8 af = *(const bf16x8*)&act2[(t*16 + l15) * ASTR + ks*32 + quad*8];
            acc[t] = __builtin_amdgcn_mfma_f32_16x16x32_bf16(af, bw2[ks], acc[t], 0, 0, 0);
        }
    }
    #pragma unroll
    for (int t = 0; t < 4; ++t) {
        const unsigned p01 = cvtpk(fmaxf(acc[t][0], 0.0f), fmaxf(acc[t][1], 0.0f));
        const unsigned p23 = cvtpk(fmaxf(acc[t][2], 0.0f), fmaxf(acc[t][3], 0.0f));
        act[(t*16 + quad*4 + 0) * ASTR + nn] = (short)(p01 & 0xffffu);
        act[(t*16 + quad*4 + 1) * ASTR + nn] = (short)(p01 >> 16);
        act[(t*16 + quad*4 + 2) * ASTR + nn] = (short)(p23 & 0xffffu);
        act[(t*16 + quad*4 + 3) * ASTR + nn] = (short)(p23 >> 16);
    }
    __syncthreads();   // B3: act(emb) ready

    // ===== phase 4: heads via MFMA (wave s = m-tile s; n<6 used) =====
    {
        f32x4 yac = (f32x4){0.0f, 0.0f, 0.0f, 0.0f};
        #pragma unroll
        for (int ks = 0; ks < 2; ++ks) {
            const bf16x8 af = *(const bf16x8*)&act[(s*16 + l15) * ASTR + ks*32 + quad*8];
            yac = __builtin_amdgcn_mfma_f32_16x16x32_bf16(af, bhd[ks], yac, 0, 0, 0);
        }
        #pragma unroll
        for (int r = 0; r < 4; ++r)
            red[(s*16 + quad*4 + r) * YHSTR + l15] = yac[r];
    }
    __syncthreads();   // B4: y6 ready

    // ===== phase 5: offsets/gates from y6 (identical in all slices), then
    //        sampling-2 (per-pixel offsets); fea0 fp32 in regs + bf16 LDS =====
    const float* __restrict__ yp = &red[lane * YHSTR];
    const float offx = bo[0] + yp[0];
    const float offy = bo[1] + yp[1];
    const float rg0 = 1.0f / (1.0f + __expf(-(br[0] + yp[2])));
    const float rg1 = 1.0f / (1.0f + __expf(-(br[1] + yp[3])));
    const float rg2 = 1.0f / (1.0f + __expf(-(br[2] + yp[4])));
    const float rg3 = 1.0f / (1.0f + __expf(-(br[3] + yp[5])));

    float f[SC];
    {
        int p0, p1;
        float u0, u1, t0, t1;
        bilin_pair(gx + offx * (2.0f / (WIN - 1)),
                   gy + offy * (2.0f / (HIN - 1)),
                   p0, p1, u0, u1, t0, t1);
        #pragma unroll
        for (int kb = 0; kb < SC; kb += 8) {
            float2 a[8], b[8];
            #pragma unroll
            for (int k = 0; k < 8; ++k) {
                const float* __restrict__ xc = xb + (cb + kb + k) * HW;
                a[k] = *(const float2*)(xc + p0);
                b[k] = *(const float2*)(xc + p1);
            }
            #pragma unroll
            for (int k = 0; k < 8; ++k)
                f[kb + k] = fmaf(a[k].x, u0, fmaf(a[k].y, u1,
                            fmaf(b[k].x, t0, b[k].y * t1)));
        }
        u32x4 v0, v1;
        #pragma unroll
        for (int d = 0; d < 4; ++d) {
            v0[d] = cvtpk(f[2*d],     f[2*d + 1]);
            v1[d] = cvtpk(f[8 + 2*d], f[8 + 2*d + 1]);
        }
        *(u32x4*)&act[lane * ASTR + cb]     = v0;   // overwrite emb
        *(u32x4*)&act[lane * ASTR + cb + 8] = v1;
    }
    __syncthreads();   // B5: act(fea0) visible; all y6 reads done

    // ===== phase 6: GEMM-1  y[pix][eo] = fea0 x wcm^T  (2 m-tiles/wave) =====
    {
        const int mb = (s >> 1) * 2;
        #pragma unroll
        for (int mi = 0; mi < 2; ++mi) {
            const int mt = mb + mi;
            f32x4 yac = (f32x4){0.0f, 0.0f, 0.0f, 0.0f};
            #pragma unroll
            for (int ks = 0; ks < 2; ++ks) {
                const bf16x8 af = *(const bf16x8*)&act[(mt*16 + l15) * ASTR + ks*32 + quad*8];
                yac = __builtin_amdgcn_mfma_f32_16x16x32_bf16(af, bwc[ks], yac, 0, 0, 0);
            }
            #pragma unroll
            for (int r = 0; r < 4; ++r)
                red[(mt*16 + quad*4 + r) * YSTR + nt1*16 + l15] = yac[r];
        }
    }
    __syncthreads();   // B6: y32 ready

    // ===== phase 7: per-pixel gate fold: comp[d], t[ed] -> bf16 act[pix][0..31] =====
    {
        float comp[8];
        const float* __restrict__ yr = &red[lane * YSTR];
        #pragma unroll
        for (int d = 0; d < 8; ++d) {
            float v = rg0 * yr[d];
            v = fmaf(rg1, yr[8 + d],  v);
            v = fmaf(rg2, yr[16 + d], v);
            v = fmaf(rg3, yr[24 + d], v);
            comp[d] = v;
        }
        u32x4 T0, T1, T2, T3;
        #pragma unroll
        for (int d = 0; d < 4; ++d) {
            T0[d] = cvtpk(rg0 * comp[2*d], rg0 * comp[2*d + 1]);
            T1[d] = cvtpk(rg1 * comp[2*d], rg1 * comp[2*d + 1]);
            T2[d] = cvtpk(rg2 * comp[2*d], rg2 * comp[2*d + 1]);
            T3[d] = cvtpk(rg3 * comp[2*d], rg3 * comp[2*d + 1]);
        }
        // GEMM-1's act reads completed before B6; t writes target act while
        // y32 reads hit red -- disjoint arrays. Safe.
        *(u32x4*)&act[lane * ASTR + 0]  = T0;
        *(u32x4*)&act[lane * ASTR + 8]  = T1;
        *(u32x4*)&act[lane * ASTR + 16] = T2;
        *(u32x4*)&act[lane * ASTR + 24] = T3;
    }
    __syncthreads();   // B7: t-matrix ready

    // ===== phase 8: GEMM-2  expand[pix][c] = t x wexR^T  (4 m-tiles/wave) =====
    #pragma unroll
    for (int t = 0; t < 4; ++t) {
        f32x4 oac = (f32x4){0.0f, 0.0f, 0.0f, 0.0f};
        const bf16x8 af = *(const bf16x8*)&act[(t*16 + l15) * ASTR + quad*8];
        oac = __builtin_amdgcn_mfma_f32_16x16x32_bf16(af, bwe, oac, 0, 0, 0);
        #pragma unroll
        for (int r = 0; r < 4; ++r)
            red[(t*16 + quad*4 + r) * OSTR + nn] = oac[r];
    }
    __syncthreads();   // B8: expand ready

    // ===== phase 9: residual + coalesced store (pixel=lane, my 16 ch) =====
    float* __restrict__ ob = out + bb * (C * OH * OW) + oy * OW + ox;
    const float* __restrict__ orow = &red[lane * OSTR + cb];
    #pragma unroll
    for (int kk = 0; kk < SC; kk += 4) {
        const float4 e4 = *(const float4*)(orow + kk);
        ob[(cb + kk + 0) * (OH * OW)] = f[kk + 0] + e4.x;
        ob[(cb + kk + 1) * (OH * OW)] = f[kk + 1] + e4.y;
        ob[(cb + kk + 2) * (OH * OW)] = f[kk + 2] + e4.z;
        ob[(cb + kk + 3) * (OH * OW)] = f[kk + 3] + e4.w;
    }
}

extern "C" void kernel_launch(void* const* d_in, const int* in_sizes, int n_in,
                              void* d_out, int out_size, void* d_ws, size_t ws_size,
                              hipStream_t stream) {
    const float* x   = (const float*)d_in[0];
    const float* wcm = (const float*)d_in[1];
    const float* wex = (const float*)d_in[2];
    const float* w1  = (const float*)d_in[3];
    const float* b1  = (const float*)d_in[4];
    const float* w2  = (const float*)d_in[5];
    const float* b2  = (const float*)d_in[6];
    const float* wr  = (const float*)d_in[7];
    const float* br  = (const float*)d_in[8];
    const float* wo  = (const float*)d_in[9];
    const float* bo  = (const float*)d_in[10];
    float* out = (float*)d_out;
    unsigned short* wsb = (unsigned short*)d_ws;

    // prep: pack weights to bf16 in ws (same work every call; stream-ordered)
    prep_kernel<<<(WS_TOT + 255) / 256, 256, 0, stream>>>(wcm, wex, w1, w2, wr, wo, wsb);

    const int total  = BATCH * OH * OW;    // 131072 pixels
    const int blocks = total / PIX;        // 2048 blocks of 256 threads
    scab_kernel<<<blocks, BLK, 0, stream>>>(x, w1, b1, b2, br, bo, wsb, out);
}